// Round 4
// baseline (294.805 us; speedup 1.0000x reference)
//
#include <hip/hip_runtime.h>

// Volume renderer: alpha-compositing over 192 samples per ray.
// v5: PERSISTENT waves + software-pipelined ray loop (prefetch next ray's
// registers while computing the current ray).
//
// Post-mortem v2-v4: three structurally different kernels all ran 103 us at
// 1.73 TB/s. VGPR counts (20/20/36) show the scheduler kept re-serializing
// the loads; short-lived one-ray waves restart the latency chain every time,
// leaving ~2 loads in flight per CU (Little's law at 1.7 TB/s x 400 ns).
//
// v5 structure:
//  * 8192 persistent waves (2048 blocks x 4), each owns 8 rays strided by
//    8192 (device-wide access stays contiguous at any instant).
//  * Loop body: issue ray i's 6 loads (5x dwordx4 + 1 dword) ->
//    sched_barrier(0) -> compute+store ray i-1 -> rotate registers.
//    The prefetch's first use is a full compute phase (~700 cy of exp/DPP/
//    FMA work) downstream, so the compiler's own waitcnt placement hides
//    the latency. Loop-carried liveness forces the values to stay in
//    registers -- the allocator cannot re-serialize without breaking the
//    rotation. Expected VGPR ~80-110.
//  * Per-ray math identical to v3 (48 active lanes, 4 samples/lane,
//    DPP scans) -- verified passing, absmax 0.015625.

#define NRAYS 65536
#define L 192
#define BORDER_W 1e10f
#define EPS_F 1e-10f
#define NWAVES 8192
#define RPW (NRAYS / NWAVES)   // 8 rays per persistent wave

// DPP helper: invalid-source / masked-row lanes receive `old` (identity).
template <int CTRL, int RMASK>
__device__ __forceinline__ float updpp(float old, float src) {
    return __int_as_float(__builtin_amdgcn_update_dpp(
        __float_as_int(old), __float_as_int(src), CTRL, RMASK, 0xf, false));
}

// Inclusive product scan across the 64-lane wave (6 DPP VALU ops).
__device__ __forceinline__ float wave_incl_prod(float p) {
    p *= updpp<0x111, 0xf>(1.0f, p);  // row_shr:1
    p *= updpp<0x112, 0xf>(1.0f, p);  // row_shr:2
    p *= updpp<0x114, 0xf>(1.0f, p);  // row_shr:4
    p *= updpp<0x118, 0xf>(1.0f, p);  // row_shr:8
    p *= updpp<0x142, 0xa>(1.0f, p);  // row_bcast:15 -> rows 1,3
    p *= updpp<0x143, 0xc>(1.0f, p);  // row_bcast:31 -> rows 2,3
    return p;
}

// Inclusive sum scan: after this, lane 63 holds the wave total.
#define SUMSCAN(v)                          \
    v += updpp<0x111, 0xf>(0.0f, v);        \
    v += updpp<0x112, 0xf>(0.0f, v);        \
    v += updpp<0x114, 0xf>(0.0f, v);        \
    v += updpp<0x118, 0xf>(0.0f, v);        \
    v += updpp<0x142, 0xa>(0.0f, v);        \
    v += updpp<0x143, 0xc>(0.0f, v);

__device__ __forceinline__ float fast_sigmoid(float x) {
    return __builtin_amdgcn_rcpf(1.0f + __expf(-x));
}

struct Ray {
    float4 dv, sv, r0, r1, r2;
    float d4;
};

__device__ __forceinline__ Ray load_ray(const float* __restrict__ depth,
                                        const float* __restrict__ rgb,
                                        const float* __restrict__ sigma,
                                        int ray, int cl) {
    Ray rd;
    const size_t sbase = (size_t)ray * L + cl * 4;
    rd.dv = *reinterpret_cast<const float4*>(depth + sbase);
    rd.sv = *reinterpret_cast<const float4*>(sigma + sbase);
    const float* rp = rgb + (size_t)ray * (L * 3) + cl * 12;
    rd.r0 = *reinterpret_cast<const float4*>(rp + 0);
    rd.r1 = *reinterpret_cast<const float4*>(rp + 4);
    rd.r2 = *reinterpret_cast<const float4*>(rp + 8);
    size_t i4 = sbase + 4;
    if (i4 > (size_t)NRAYS * L - 1) i4 = (size_t)NRAYS * L - 1;
    rd.d4 = depth[i4];
    return rd;
}

__device__ __forceinline__ void process_ray(const Ray& rd, int ray, int lane,
                                            bool active,
                                            float* __restrict__ out) {
    const size_t sbase = (size_t)ray * L + ((lane < 48) ? lane : 47) * 4;

    float delta0 = rd.dv.y - rd.dv.x;
    float delta1 = rd.dv.z - rd.dv.y;
    float delta2 = rd.dv.w - rd.dv.z;
    float delta3 = (lane == 47) ? BORDER_W : (rd.d4 - rd.dv.w);

    float e0 = __expf(-fmaxf(rd.sv.x, 0.0f) * delta0);
    float e1 = __expf(-fmaxf(rd.sv.y, 0.0f) * delta1);
    float e2 = __expf(-fmaxf(rd.sv.z, 0.0f) * delta2);
    float e3 = __expf(-fmaxf(rd.sv.w, 0.0f) * delta3);
    float surv0 = e0 + EPS_F, surv1 = e1 + EPS_F;
    float surv2 = e2 + EPS_F, surv3 = e3 + EPS_F;

    float p01   = surv0 * surv1;
    float p012  = p01 * surv2;
    float p0123 = p012 * surv3;

    // sigmoids are independent of the scan -> fill latency slots
    float g0 = fast_sigmoid(rd.r0.x), g1 = fast_sigmoid(rd.r0.y), g2 = fast_sigmoid(rd.r0.z);
    float g3 = fast_sigmoid(rd.r0.w), g4 = fast_sigmoid(rd.r1.x), g5 = fast_sigmoid(rd.r1.y);
    float g6 = fast_sigmoid(rd.r1.z), g7 = fast_sigmoid(rd.r1.w), g8 = fast_sigmoid(rd.r2.x);
    float g9 = fast_sigmoid(rd.r2.y), gA = fast_sigmoid(rd.r2.z), gB = fast_sigmoid(rd.r2.w);

    // wave-wide inclusive product scan (DPP, VALU-only)
    float p = wave_incl_prod(p0123);

    float excl = __shfl_up(p, 1, 64);
    if (lane == 0) excl = 1.0f;

    float T0 = excl;
    float T1 = excl * surv0;
    float T2 = excl * p01;
    float T3 = excl * p012;
    float w0 = (1.0f - e0) * T0;
    float w1 = (1.0f - e1) * T1;
    float w2 = (1.0f - e2) * T2;
    float w3 = (1.0f - e3) * T3;

    if (!active) { w0 = w1 = w2 = w3 = 0.0f; }

    if (active) {
        *reinterpret_cast<float4*>(out + (size_t)NRAYS * 5 + sbase) =
            make_float4(w0, w1, w2, w3);
    }

    float col0 = w0 * g0 + w1 * g3 + w2 * g6 + w3 * g9;
    float col1 = w0 * g1 + w1 * g4 + w2 * g7 + w3 * gA;
    float col2 = w0 * g2 + w1 * g5 + w2 * g8 + w3 * gB;
    float dep  = w0 * rd.dv.x + w1 * rd.dv.y + w2 * rd.dv.z + w3 * rd.dv.w;
    float acc  = w0 + w1 + w2 + w3;

    SUMSCAN(col0)
    SUMSCAN(col1)
    SUMSCAN(col2)
    SUMSCAN(dep)
    SUMSCAN(acc)

    if (lane == 63) {
        out[(size_t)ray * 3 + 0] = col0;
        out[(size_t)ray * 3 + 1] = col1;
        out[(size_t)ray * 3 + 2] = col2;
        out[(size_t)NRAYS * 3 + ray] = dep;
        out[(size_t)NRAYS * 4 + ray] = acc;
    }
}

__global__ __launch_bounds__(256) void vol_render_kernel(
    const float* __restrict__ depth,   // [N, 192]
    const float* __restrict__ rgb,     // [N, 192, 3]
    const float* __restrict__ sigma,   // [N, 192]
    float* __restrict__ out)           // color N*3 | depth N | acc N | weights N*192
{
    const int lane = threadIdx.x & 63;
    const int wave = threadIdx.x >> 6;
    const int waveId = blockIdx.x * 4 + wave;        // 0..8191
    const int cl = (lane < 48) ? lane : 47;          // clamped lane (no branch)
    const bool active = lane < 48;

    // prologue: load ray 0 of this wave
    Ray cur = load_ray(depth, rgb, sigma, waveId, cl);

#pragma unroll
    for (int i = 1; i <= RPW; ++i) {
        Ray nxt;
        if (i < RPW) {
            // prefetch next ray's 6 loads, pinned here by the fence
            nxt = load_ray(depth, rgb, sigma, waveId + i * NWAVES, cl);
        }
        __builtin_amdgcn_sched_barrier(0);
        // compute current ray: ~700 cycles of exp/DPP/FMA covering the
        // prefetch latency
        process_ray(cur, waveId + (i - 1) * NWAVES, lane, active, out);
        if (i < RPW) cur = nxt;   // register rotation (renaming after unroll)
    }
}

extern "C" void kernel_launch(void* const* d_in, const int* in_sizes, int n_in,
                              void* d_out, int out_size, void* d_ws, size_t ws_size,
                              hipStream_t stream) {
    const float* depth = (const float*)d_in[0];
    const float* rgb   = (const float*)d_in[1];
    const float* sigma = (const float*)d_in[2];
    float* out = (float*)d_out;

    // 8192 persistent waves: 2048 blocks x 4 waves, 8 rays each
    dim3 grid(NWAVES / 4);
    dim3 block(256);
    vol_render_kernel<<<grid, block, 0, stream>>>(depth, rgb, sigma, out);
}

// Round 5
// 292.694 us; speedup vs baseline: 1.0072x; 1.0072x over previous
//
#include <hip/hip_runtime.h>

// Volume renderer: alpha-compositing over 192 samples per ray.
// v6: inline-asm load block -- take MLP away from the compiler.
//
// Post-mortem v2-v5: four structurally different kernels (scalar, float4,
// 2-ray + sched_barrier, persistent software pipeline) ALL ran ~103 us at
// ~1.7 TB/s HBM, VGPR 20/20/36/32. The compiler re-serialized the loads in
// every version (load->waitcnt->use->reuse regs), capping in-flight loads
// per wave at ~2. Source-level scheduling hints have failed three times.
//
// v6: ONE asm volatile block issues all 6 loads back-to-back and does its
// own s_waitcnt vmcnt(0). The loaded values are asm OUTPUTS:
//  * the register allocator MUST assign 21 distinct live VGPRs (no
//    splitting/sinking inside an asm blob)  -> VGPR ~56 expected;
//  * guaranteed memory-level parallelism of 6 per wave, ~190 outstanding
//    requests per CU at 32 waves/CU (vs ~4 before);
//  * waitcnt is in the same blob as the loads, consumers are ordered by
//    SSA data deps on the outputs -> no hoist hazard.
// Compute structure = v3 (proven: 48 active lanes, 4 samples/lane, DPP
// scans, absmax 0.015625).

#define NRAYS 65536
#define L 192
#define BORDER_W 1e10f
#define EPS_F 1e-10f

typedef float f32x4 __attribute__((ext_vector_type(4)));

// DPP helper: invalid-source / masked-row lanes receive `old` (identity).
template <int CTRL, int RMASK>
__device__ __forceinline__ float updpp(float old, float src) {
    return __int_as_float(__builtin_amdgcn_update_dpp(
        __float_as_int(old), __float_as_int(src), CTRL, RMASK, 0xf, false));
}

// Inclusive product scan across the 64-lane wave (6 DPP VALU ops).
__device__ __forceinline__ float wave_incl_prod(float p) {
    p *= updpp<0x111, 0xf>(1.0f, p);  // row_shr:1
    p *= updpp<0x112, 0xf>(1.0f, p);  // row_shr:2
    p *= updpp<0x114, 0xf>(1.0f, p);  // row_shr:4
    p *= updpp<0x118, 0xf>(1.0f, p);  // row_shr:8
    p *= updpp<0x142, 0xa>(1.0f, p);  // row_bcast:15 -> rows 1,3
    p *= updpp<0x143, 0xc>(1.0f, p);  // row_bcast:31 -> rows 2,3
    return p;
}

// Inclusive sum scan: after this, lane 63 holds the wave total.
#define SUMSCAN(v)                          \
    v += updpp<0x111, 0xf>(0.0f, v);        \
    v += updpp<0x112, 0xf>(0.0f, v);        \
    v += updpp<0x114, 0xf>(0.0f, v);        \
    v += updpp<0x118, 0xf>(0.0f, v);        \
    v += updpp<0x142, 0xa>(0.0f, v);        \
    v += updpp<0x143, 0xc>(0.0f, v);

__device__ __forceinline__ float fast_sigmoid(float x) {
    return __builtin_amdgcn_rcpf(1.0f + __expf(-x));
}

__global__ __launch_bounds__(256) void vol_render_kernel(
    const float* __restrict__ depth,   // [N, 192]
    const float* __restrict__ rgb,     // [N, 192, 3]
    const float* __restrict__ sigma,   // [N, 192]
    float* __restrict__ out)           // color N*3 | depth N | acc N | weights N*192
{
    const int lane = threadIdx.x & 63;
    const int wave = threadIdx.x >> 6;
    const int ray  = blockIdx.x * 4 + wave;

    const int  cl     = (lane < 48) ? lane : 47;   // clamped lane (no branch)
    const bool active = lane < 48;
    const size_t sbase = (size_t)ray * L + cl * 4;

    size_t i4 = sbase + 4;                          // boundary-depth index
    if (i4 > (size_t)NRAYS * L - 1) i4 = (size_t)NRAYS * L - 1;

    const float* dp  = depth + sbase;
    const float* sp  = sigma + sbase;
    const float* rp  = rgb + (size_t)ray * (L * 3) + cl * 12;
    const float* d4p = depth + i4;

    // ---- forced-MLP load block: 6 loads in flight, one waitcnt ----
    f32x4 dv, sv, r0, r1, r2;
    float d4;
    asm volatile(
        "global_load_dwordx4 %0, %6, off\n\t"
        "global_load_dwordx4 %1, %7, off\n\t"
        "global_load_dwordx4 %2, %8, off\n\t"
        "global_load_dwordx4 %3, %8, off offset:16\n\t"
        "global_load_dwordx4 %4, %8, off offset:32\n\t"
        "global_load_dword   %5, %9, off\n\t"
        "s_waitcnt vmcnt(0)"
        : "=&v"(dv), "=&v"(sv), "=&v"(r0), "=&v"(r1), "=&v"(r2), "=&v"(d4)
        : "v"(dp), "v"(sp), "v"(rp), "v"(d4p)
        : "memory");

    // ---- alpha / survival ----
    float delta0 = dv.y - dv.x;
    float delta1 = dv.z - dv.y;
    float delta2 = dv.w - dv.z;
    float delta3 = (lane == 47) ? BORDER_W : (d4 - dv.w);

    float e0 = __expf(-fmaxf(sv.x, 0.0f) * delta0);
    float e1 = __expf(-fmaxf(sv.y, 0.0f) * delta1);
    float e2 = __expf(-fmaxf(sv.z, 0.0f) * delta2);
    float e3 = __expf(-fmaxf(sv.w, 0.0f) * delta3);
    float surv0 = e0 + EPS_F, surv1 = e1 + EPS_F;
    float surv2 = e2 + EPS_F, surv3 = e3 + EPS_F;

    // in-lane prefix products
    float p01   = surv0 * surv1;
    float p012  = p01 * surv2;
    float p0123 = p012 * surv3;

    // sigmoids: independent of the scan -> scheduler interleaves them
    float g0 = fast_sigmoid(r0.x), g1 = fast_sigmoid(r0.y), g2 = fast_sigmoid(r0.z);
    float g3 = fast_sigmoid(r0.w), g4 = fast_sigmoid(r1.x), g5 = fast_sigmoid(r1.y);
    float g6 = fast_sigmoid(r1.z), g7 = fast_sigmoid(r1.w), g8 = fast_sigmoid(r2.x);
    float g9 = fast_sigmoid(r2.y), gA = fast_sigmoid(r2.z), gB = fast_sigmoid(r2.w);

    // ---- wave-wide inclusive product scan (DPP, VALU-only) ----
    float p = wave_incl_prod(p0123);

    float excl = __shfl_up(p, 1, 64);
    if (lane == 0) excl = 1.0f;

    // transmittance & weights for the 4 owned samples
    float T0 = excl;
    float T1 = excl * surv0;
    float T2 = excl * p01;
    float T3 = excl * p012;
    float w0 = (1.0f - e0) * T0;
    float w1 = (1.0f - e1) * T1;
    float w2 = (1.0f - e2) * T2;
    float w3 = (1.0f - e3) * T3;

    if (!active) { w0 = w1 = w2 = w3 = 0.0f; }

    // coalesced float4 weight store
    if (active) {
        *reinterpret_cast<f32x4*>(out + (size_t)NRAYS * 5 + sbase) =
            (f32x4){w0, w1, w2, w3};
    }

    float col0 = w0 * g0 + w1 * g3 + w2 * g6 + w3 * g9;
    float col1 = w0 * g1 + w1 * g4 + w2 * g7 + w3 * gA;
    float col2 = w0 * g2 + w1 * g5 + w2 * g8 + w3 * gB;
    float dep  = w0 * dv.x + w1 * dv.y + w2 * dv.z + w3 * dv.w;
    float acc  = w0 + w1 + w2 + w3;

    // ---- 5 wave sums via DPP sum-scan; totals land in lane 63 ----
    SUMSCAN(col0)
    SUMSCAN(col1)
    SUMSCAN(col2)
    SUMSCAN(dep)
    SUMSCAN(acc)

    if (lane == 63) {
        out[(size_t)ray * 3 + 0] = col0;
        out[(size_t)ray * 3 + 1] = col1;
        out[(size_t)ray * 3 + 2] = col2;
        out[(size_t)NRAYS * 3 + ray] = dep;
        out[(size_t)NRAYS * 4 + ray] = acc;
    }
}

extern "C" void kernel_launch(void* const* d_in, const int* in_sizes, int n_in,
                              void* d_out, int out_size, void* d_ws, size_t ws_size,
                              hipStream_t stream) {
    const float* depth = (const float*)d_in[0];
    const float* rgb   = (const float*)d_in[1];
    const float* sigma = (const float*)d_in[2];
    float* out = (float*)d_out;

    // 4 waves (rays) per 256-thread block
    dim3 grid(NRAYS / 4);
    dim3 block(256);
    vol_render_kernel<<<grid, block, 0, stream>>>(depth, rgb, sigma, out);
}